// Round 1
// baseline (2056.457 us; speedup 1.0000x reference)
//
#include <hip/hip_runtime.h>

// Problem constants (from setup_inputs): B=4, T=2048, H=16, K=128, V=128
constexpr int Bc = 4, Tc = 2048, Hc = 16, Kc = 128, Vc = 128;
constexpr float EPSc = 1e-6f;
constexpr float SCALEc = 0.08838834764831845f; // 128^-0.5

__device__ __forceinline__ float rsqrt_nr(float s) {
  // rsqrt + one Newton step for f32-accurate 1/sqrt
  float r = rsqrtf(s);
  r = r * (1.5f - 0.5f * s * r * r);
  return r;
}

// Pass 1: l2-normalize q (and * K^-0.5) and k along last axis (K=128).
// One wave per (b,t,h) row; handles the q-row and k-row together.
__global__ __launch_bounds__(256) void norm_qk(const float* __restrict__ q,
                                               const float* __restrict__ k,
                                               float* __restrict__ qn,
                                               float* __restrict__ kn) {
  const int rows = Bc * Tc * Hc;
  int gtid = blockIdx.x * 256 + threadIdx.x;
  int row = gtid >> 6;
  int lane = gtid & 63;
  if (row >= rows) return;
  const float2 vq = ((const float2*)(q + (size_t)row * Kc))[lane];
  const float2 vk = ((const float2*)(k + (size_t)row * Kc))[lane];
  float sq = vq.x * vq.x + vq.y * vq.y;
  float sk = vk.x * vk.x + vk.y * vk.y;
#pragma unroll
  for (int m = 1; m < 64; m <<= 1) {
    sq += __shfl_xor(sq, m);
    sk += __shfl_xor(sk, m);
  }
  float rq = rsqrt_nr(sq + EPSc) * SCALEc;
  float rk = rsqrt_nr(sk + EPSc);
  float2 oq = {vq.x * rq, vq.y * rq};
  float2 ok = {vk.x * rk, vk.y * rk};
  ((float2*)(qn + (size_t)row * Kc))[lane] = oq;
  ((float2*)(kn + (size_t)row * Kc))[lane] = ok;
}

// Pass 2: sequential gated delta-rule scan.
// Grid: B*H*4 blocks (V split 4 ways -> 32 columns per block), 256 threads.
// Thread (tk = tid&7, tv = tid>>3) owns state S[k0..k0+15][vcol] in registers.
// k-reductions are 3-step shfl_xor butterflies within 8 lanes.
template <bool PRENORM>
__global__ __launch_bounds__(256) void gdn_scan(
    const float* __restrict__ q, const float* __restrict__ k,
    const float* __restrict__ v, const float* __restrict__ g,
    const float* __restrict__ beta, const float* __restrict__ s0,
    float* __restrict__ o, float* __restrict__ fs) {
  const int bid = blockIdx.x;
  const int vb = bid & 3;    // which 32-column V block
  const int bh = bid >> 2;   // b*H + h
  const int b = bh >> 4;
  const int h = bh & 15;
  const int tid = threadIdx.x;
  const int tk = tid & 7;    // 8 k-groups of 16
  const int tv = tid >> 3;   // 32 columns
  const int vcol = vb * 32 + tv;
  const int k0 = tk * 16;

  // State in registers
  float S[16];
  {
    const float* s0p = s0 + ((size_t)bh * Kc + k0) * Vc + vcol;
#pragma unroll
    for (int i = 0; i < 16; ++i) S[i] = s0p[(size_t)i * Vc];
  }

  const size_t qk_base = (size_t)b * Tc * Hc * Kc + (size_t)h * Kc + k0;
  const size_t v_base = (size_t)b * Tc * Hc * Vc + (size_t)h * Vc + vcol;
  const size_t gb_base = (size_t)b * Tc * Hc + h;
  const size_t qk_stride = (size_t)Hc * Kc;  // per time step
  const size_t v_stride = (size_t)Hc * Vc;
  const size_t gb_stride = (size_t)Hc;

  float4 cq[4], ck[4];
  float cv, cg, cb;
  {
    const float* qrow = q + qk_base;
    const float* krow = k + qk_base;
#pragma unroll
    for (int i = 0; i < 4; ++i) {
      cq[i] = ((const float4*)qrow)[i];
      ck[i] = ((const float4*)krow)[i];
    }
    cv = v[v_base];
    cg = g[gb_base];
    cb = beta[gb_base];
  }

  for (int t = 0; t < Tc; ++t) {
    // Software prefetch of step t+1 (independent of the state chain)
    float4 nq[4], nk[4];
    float nv, ng, nb;
    {
      int tn = (t + 1 < Tc) ? (t + 1) : t;
      const float* qrow = q + qk_base + (size_t)tn * qk_stride;
      const float* krow = k + qk_base + (size_t)tn * qk_stride;
#pragma unroll
      for (int i = 0; i < 4; ++i) {
        nq[i] = ((const float4*)qrow)[i];
        nk[i] = ((const float4*)krow)[i];
      }
      nv = v[v_base + (size_t)tn * v_stride];
      ng = g[gb_base + (size_t)tn * gb_stride];
      nb = beta[gb_base + (size_t)tn * gb_stride];
    }

    float qn_[16], kn_[16];
#pragma unroll
    for (int i = 0; i < 4; ++i) {
      qn_[4 * i + 0] = cq[i].x; qn_[4 * i + 1] = cq[i].y;
      qn_[4 * i + 2] = cq[i].z; qn_[4 * i + 3] = cq[i].w;
      kn_[4 * i + 0] = ck[i].x; kn_[4 * i + 1] = ck[i].y;
      kn_[4 * i + 2] = ck[i].z; kn_[4 * i + 3] = ck[i].w;
    }

    if (!PRENORM) {
      float sq = 0.f, sk = 0.f;
#pragma unroll
      for (int i = 0; i < 16; ++i) {
        sq = fmaf(qn_[i], qn_[i], sq);
        sk = fmaf(kn_[i], kn_[i], sk);
      }
#pragma unroll
      for (int m = 1; m < 8; m <<= 1) {
        sq += __shfl_xor(sq, m);
        sk += __shfl_xor(sk, m);
      }
      float rq = rsqrt_nr(sq + EPSc) * SCALEc;
      float rk = rsqrt_nr(sk + EPSc);
#pragma unroll
      for (int i = 0; i < 16; ++i) {
        qn_[i] *= rq;
        kn_[i] *= rk;
      }
    }

    float eg = expf(cg);

    // pred = eg * (kn . S_old), reduced over k
    float p0 = 0.f, p1 = 0.f, p2 = 0.f, p3 = 0.f;
#pragma unroll
    for (int i = 0; i < 16; i += 4) {
      p0 = fmaf(kn_[i + 0], S[i + 0], p0);
      p1 = fmaf(kn_[i + 1], S[i + 1], p1);
      p2 = fmaf(kn_[i + 2], S[i + 2], p2);
      p3 = fmaf(kn_[i + 3], S[i + 3], p3);
    }
    float pred = (p0 + p1) + (p2 + p3);
#pragma unroll
    for (int m = 1; m < 8; m <<= 1) pred += __shfl_xor(pred, m);
    pred *= eg;

    float vadj = (cv - pred) * cb;

    // S = eg*S + kn * vadj
#pragma unroll
    for (int i = 0; i < 16; ++i) S[i] = fmaf(S[i], eg, kn_[i] * vadj);

    // out = qn . S_new, reduced over k
    float o0 = 0.f, o1 = 0.f, o2 = 0.f, o3 = 0.f;
#pragma unroll
    for (int i = 0; i < 16; i += 4) {
      o0 = fmaf(qn_[i + 0], S[i + 0], o0);
      o1 = fmaf(qn_[i + 1], S[i + 1], o1);
      o2 = fmaf(qn_[i + 2], S[i + 2], o2);
      o3 = fmaf(qn_[i + 3], S[i + 3], o3);
    }
    float out = (o0 + o1) + (o2 + o3);
#pragma unroll
    for (int m = 1; m < 8; m <<= 1) out += __shfl_xor(out, m);
    if (tk == 0) o[((size_t)(b * Tc + t) * Hc + h) * Vc + vcol] = out;

    // rotate prefetched registers
#pragma unroll
    for (int i = 0; i < 4; ++i) {
      cq[i] = nq[i];
      ck[i] = nk[i];
    }
    cv = nv;
    cg = ng;
    cb = nb;
  }

  // final state
  float* fsp = fs + ((size_t)bh * Kc + k0) * Vc + vcol;
#pragma unroll
  for (int i = 0; i < 16; ++i) fsp[(size_t)i * Vc] = S[i];
}

extern "C" void kernel_launch(void* const* d_in, const int* in_sizes, int n_in,
                              void* d_out, int out_size, void* d_ws, size_t ws_size,
                              hipStream_t stream) {
  const float* q = (const float*)d_in[0];
  const float* k = (const float*)d_in[1];
  const float* v = (const float*)d_in[2];
  const float* g = (const float*)d_in[3];
  const float* beta = (const float*)d_in[4];
  const float* s0 = (const float*)d_in[5];
  float* o = (float*)d_out;
  float* fs = o + (size_t)Bc * Tc * Hc * Vc;

  const size_t qk_elems = (size_t)Bc * Tc * Hc * Kc;
  const size_t need = 2 * qk_elems * sizeof(float);

  if (ws_size >= need) {
    float* qn = (float*)d_ws;
    float* kn = qn + qk_elems;
    const int rows = Bc * Tc * Hc;            // 131072 rows (one wave each)
    norm_qk<<<rows / 4, 256, 0, stream>>>(q, k, qn, kn);
    gdn_scan<true><<<Bc * Hc * 4, 256, 0, stream>>>(qn, kn, v, g, beta, s0, o, fs);
  } else {
    gdn_scan<false><<<Bc * Hc * 4, 256, 0, stream>>>(q, k, v, g, beta, s0, o, fs);
  }
}